// Round 8
// baseline (320.551 us; speedup 1.0000x reference)
//
#include <hip/hip_runtime.h>
#include <hip/hip_bf16.h>

#define FEAT   256
#define TROWS  16
#define TBYTES (TROWS * FEAT * 4)   // 16 KiB per x-tile
#define NBUF   2                    // depth-2: loads lead compute by 1 full phase

typedef __attribute__((ext_vector_type(8))) short  short8;
typedef __attribute__((ext_vector_type(4))) float  floatx4;

__device__ __forceinline__ short f2bf(float f) {
    __hip_bfloat16 h = __float2bfloat16(f);   // RTNE; pairs fuse to v_cvt_pk_bf16_f32
    return __builtin_bit_cast(short, h);
}

// Byte-offset swizzle within a 16-row x-tile: XOR bits 4..6 with row&7
// (row = offset>>10). Involution, 16 B-granular. Applied to the gload_lds
// SOURCE (dest linear, per HW) and to every LDS READ.
__device__ __forceinline__ unsigned swz(unsigned o) {
    return o ^ (((o >> 10) & 7u) << 4);
}

// R7 pipeline, re-balanced for chain overlap: NBUF=2 (32 KiB LDS) lets
// 4 blocks/CU = 16 waves/CU = 4 waves/SIMD run concurrently (was 2).
// Each SIMD now interleaves 4 independent {ds_read -> cvt -> MFMA ->
// rsqrt -> store} chains while the per-wave async gload_lds stream keeps
// HBM saturated. Counted vmcnt depth-2: at the wait, ops newer than L(it)
// are L(it+1) 4 + S(it-1) 4 = 8 -> vmcnt(8) (it=0: 4). Stores never waited.
__global__ __launch_bounds__(256, 4) void gdn_kernel(
    const float* __restrict__ x,
    const float* __restrict__ beta,
    const float* __restrict__ gamma,
    float* __restrict__ out,
    int batch)
{
    __shared__ char ldsx[NBUF * TBYTES];   // 32 KiB -> 4 blocks/CU

    const int tid  = threadIdx.x;
    const int lane = tid & 63;
    const int wave = tid >> 6;          // 0..3 -> 64-col slice
    const int l15  = lane & 15;
    const int grp  = lane >> 4;
    const int colbase = wave * 64;

    // ---- One-time: gamma fragments as bf16, 64 regs.
    // k-hat map k = ks*32 + grp*8 + i, identical for both MFMA operands
    // (self-consistent; verified on HW by R1 passing with gamma=0.1*I).
    short8 Bf[4][8];
    #pragma unroll
    for (int nt = 0; nt < 4; ++nt) {
        const int col = colbase + nt * 16 + l15;
        #pragma unroll
        for (int ks = 0; ks < 8; ++ks) {
            const int k0 = ks * 32 + grp * 8;
            short8 b;
            #pragma unroll
            for (int i = 0; i < 8; ++i)
                b[i] = f2bf(gamma[(size_t)(k0 + i) * FEAT + col]);
            Bf[nt][ks] = b;
        }
    }

    // beta_c per (nt, reg): cols colbase + nt*16 + grp*4 + r
    floatx4 bc4[4];
    #pragma unroll
    for (int nt = 0; nt < 4; ++nt) {
        floatx4 b = *(const floatx4*)(beta + colbase + nt * 16 + grp * 4);
        #pragma unroll
        for (int r = 0; r < 4; ++r) bc4[nt][r] = fmaxf(b[r], 1e-6f);
    }

    const int ntiles = batch >> 4;      // 16384
    const int stride = gridDim.x;       // 1024 -> exactly 16 iters/block
    const int iters  = ntiles / stride; // 16 (exact)
    const int t0     = blockIdx.x;

    // Async stage of tile `t` into LDS slot `s`: dest LINEAR (wave-uniform
    // base + lane*16), source pre-swizzled with the read involution.
    auto STAGE = [&](int s, int t) {
        const char* gb = (const char*)x + (size_t)t * TBYTES;
        char* lbase = &ldsx[s * TBYTES];
        #pragma unroll
        for (int r = 0; r < 4; ++r) {
            const unsigned d = (unsigned)(tid * 16 + r * 4096);
            __builtin_amdgcn_global_load_lds(
                (const __attribute__((address_space(1))) void*)(gb + swz(d)),
                (__attribute__((address_space(3))) void*)(lbase + d),
                16, 0, 0);
        }
    };

    // Prologue: 1 tile in flight before first compute.
    STAGE(0, t0);

    for (int it = 0; it < iters; ++it) {
        // Barrier A: every wave finished READING slot (it+1)&1 (at iter it-1).
        __builtin_amdgcn_s_barrier();
        __builtin_amdgcn_sched_barrier(0);

        int itn = it + 1;
        if (itn >= iters) itn = iters - 1;          // redundant tail re-stage
        STAGE((it + 1) & 1, t0 + itn * stride);     // slot-safe; never read

        // Wait ONLY for tile-it loads (in-order vmcnt); newer loads AND
        // recent stores stay in flight.
        if (it == 0) asm volatile("s_waitcnt vmcnt(4)" ::: "memory");
        else         asm volatile("s_waitcnt vmcnt(8)" ::: "memory");
        __builtin_amdgcn_sched_barrier(0);
        // Barrier B: all waves passed the wait -> tile-it fully in LDS.
        __builtin_amdgcn_s_barrier();
        __builtin_amdgcn_sched_barrier(0);

        const char* lb = &ldsx[(it & 1) * TBYTES];

        // ---- x^2 fragments (MFMA *B* operand): row l15,
        // floats [ks*32 + grp*8, +8), swizzled read.
        const unsigned p0 = (unsigned)(l15 * 1024 + grp * 32);
        const unsigned xv = (unsigned)((l15 & 7) << 4);
        short8 Af[8];
        #pragma unroll
        for (int ks = 0; ks < 8; ++ks) {
            floatx4 v0 = *(const floatx4*)(lb + ((p0 + ks * 128)      ^ xv));
            floatx4 v1 = *(const floatx4*)(lb + ((p0 + ks * 128 + 16) ^ xv));
            short8 a;
            #pragma unroll
            for (int i = 0; i < 4; ++i) {
                a[i]     = f2bf(v0[i] * v0[i]);
                a[4 + i] = f2bf(v1[i] * v1[i]);
            }
            Af[ks] = a;
        }

        // ---- MFMA over K=256, swapped: D = gamma^T . (x^2)^T
        // C/D: col(lane&15) = x-row, row(grp*4+r) = output col.
        floatx4 acc[4] = {{0.f,0.f,0.f,0.f},{0.f,0.f,0.f,0.f},
                          {0.f,0.f,0.f,0.f},{0.f,0.f,0.f,0.f}};
        #pragma unroll
        for (int ks = 0; ks < 8; ++ks) {
            #pragma unroll
            for (int nt = 0; nt < 4; ++nt) {
                acc[nt] = __builtin_amdgcn_mfma_f32_16x16x32_bf16(
                    Bf[nt][ks], Af[ks], acc[nt], 0, 0, 0);
            }
        }

        // ---- Epilogue: y = x * rsqrt(acc + beta_c), 16B-vector LDS reads
        // and stores. Lane: x-row = l15; cols = colbase + nt*16 + grp*4 + r.
        const int rb = (t0 + it * stride) << 4;
        float* orow = out + (size_t)(rb + l15) * FEAT + colbase + grp * 4;
        #pragma unroll
        for (int nt = 0; nt < 4; ++nt) {
            const unsigned eo = (unsigned)(l15 * 1024 + (colbase + nt * 16 + grp * 4) * 4);
            floatx4 xval = *(const floatx4*)(lb + (eo ^ xv));
            floatx4 y;
            #pragma unroll
            for (int r = 0; r < 4; ++r)
                y[r] = xval[r] * rsqrtf(acc[nt][r] + bc4[nt][r]);
            *(floatx4*)(orow + nt * 16) = y;
        }
        // no drain: next iter's Barrier A needs only reg-held LDS reads done.
    }
}

extern "C" void kernel_launch(void* const* d_in, const int* in_sizes, int n_in,
                              void* d_out, int out_size, void* d_ws, size_t ws_size,
                              hipStream_t stream) {
    const float* x     = (const float*)d_in[0];
    const float* beta  = (const float*)d_in[1];
    const float* gamma = (const float*)d_in[2];
    float* out = (float*)d_out;

    const int batch = in_sizes[0] / FEAT;   // 262144

    dim3 grid(1024);    // 4 blocks/CU (32 KiB LDS each), exactly 16 tiles each
    dim3 block(256);    // 4 waves: col-split within block
    hipLaunchKernelGGL(gdn_kernel, grid, block, 0, stream,
                       x, beta, gamma, out, batch);
}

// Round 9
// 148.475 us; speedup vs baseline: 2.1590x; 2.1590x over previous
//
#include <hip/hip_runtime.h>
#include <hip/hip_bf16.h>

#define FEAT   256
#define TROWS  16
#define PBYTES (TROWS * FEAT * 2)   // 8 KiB bf16 x^2 tile per buffer

typedef __attribute__((ext_vector_type(8))) short  short8;
typedef __attribute__((ext_vector_type(4))) float  floatx4;

__device__ __forceinline__ short f2bf(float f) {
    __hip_bfloat16 h = __float2bfloat16(f);   // RTNE; pairs fuse to v_cvt_pk_bf16_f32
    return __builtin_bit_cast(short, h);
}

// R9: shared bf16 x^2 tile (convert ONCE per block, not once per wave).
//  - block = 512 thr = 8 waves; wave w owns output cols [32w, 32w+32)
//    -> Bf[2][8] = 64 VGPRs -> total ~105 regs -> 4 waves/SIMD (launch_bounds 512,4)
//  - staging (T14 reg-based): thread t loads x[rb + (t&15)][(t>>4)*8 ..+8]
//    (rows are 1 KiB, 32 threads/row -> perfectly coalesced), squares, cvt_pk,
//    ONE ds_write_b128 at tid*16. Tile layout [k-chunk][row]:
//    elem (row, k) lives at (k>>3)*256 + row*16 + (k&7)*2.
//  - frag read (swapped-MFMA B-operand, lane=(grp,l15): row=l15, k0=ks*32+grp*8):
//    ds_read_b128 at grp*256 + l15*16 + ks*1024 -> ks folds into offset:N,
//    16-lane group reads 256 B contiguous -> 2-way banks (free). No swizzle.
//  - raw s_barrier with ONLY lgkmcnt(0) (no vmcnt drain): the just-issued
//    global prefetch loads ride across the barrier and land under MFMA+epilogue.
//  - NBUF=2, one barrier/iter: write(t+2 -> buf[t&1]) is after barrier(t+1),
//    all reads(t) are consumed before barrier(t+1) -> rendezvous-safe.
//  - epilogue re-reads x from global: 16 KiB tile loaded last iter -> L2-hot
//    (R1-proven: FETCH stays ~1x of x).
__global__ __launch_bounds__(512, 4) void gdn_kernel(
    const float* __restrict__ x,
    const float* __restrict__ beta,
    const float* __restrict__ gamma,
    float* __restrict__ out,
    int batch)
{
    __shared__ char ldsP[2 * PBYTES];   // 16 KiB

    const int tid  = threadIdx.x;
    const int lane = tid & 63;
    const int wave = tid >> 6;          // 0..7 -> 32-col slice
    const int l15  = lane & 15;
    const int grp  = lane >> 4;
    const int colbase = wave * 32;

    // ---- One-time: gamma fragments (A-operand of swapped MFMA), 64 regs.
    // Bf[nt][ks] elem i = gamma[ks*32 + grp*8 + i][colbase + nt*16 + l15]
    // (same k-hat map as the x^2 fragments; layout HW-verified by R7 passing).
    short8 Bf[2][8];
    #pragma unroll
    for (int nt = 0; nt < 2; ++nt) {
        const int col = colbase + nt * 16 + l15;
        #pragma unroll
        for (int ks = 0; ks < 8; ++ks) {
            const int k0 = ks * 32 + grp * 8;
            short8 b;
            #pragma unroll
            for (int i = 0; i < 8; ++i)
                b[i] = f2bf(gamma[(size_t)(k0 + i) * FEAT + col]);
            Bf[nt][ks] = b;
        }
    }

    // beta_c per (nt, reg r): output cols colbase + nt*16 + grp*4 + r
    floatx4 bc4[2];
    #pragma unroll
    for (int nt = 0; nt < 2; ++nt) {
        floatx4 b = *(const floatx4*)(beta + colbase + nt * 16 + grp * 4);
        #pragma unroll
        for (int r = 0; r < 4; ++r) bc4[nt][r] = fmaxf(b[r], 1e-6f);
    }

    const int stride = gridDim.x;               // 512
    const int iters  = (batch / TROWS) / stride;// 32 (exact)
    const int t0     = blockIdx.x;

    const int srow   = tid & 15;        // staging: my x-row within tile
    const int schunk = tid >> 4;        // my 8-float k-chunk (0..31)
    const int rdoff  = grp * 256 + l15 * 16;    // frag-read base in tile

    // Prologue: prefetch tile t0 into regs.
    floatx4 pf0, pf1;
    {
        const float* g = x + (size_t)(t0 * TROWS + srow) * FEAT + schunk * 8;
        pf0 = ((const floatx4*)g)[0];
        pf1 = ((const floatx4*)g)[1];
    }

    for (int it = 0; it < iters; ++it) {
        char* pb = ldsP + (it & 1) * PBYTES;

        // ---- stage: x^2 -> bf16 -> LDS (one b128 write per thread)
        short8 w;
        #pragma unroll
        for (int i = 0; i < 4; ++i) {
            w[i]     = f2bf(pf0[i] * pf0[i]);
            w[4 + i] = f2bf(pf1[i] * pf1[i]);
        }
        *(short8*)(pb + tid * 16) = w;

        // ---- issue prefetch for tile it+1 (rides across the barrier)
        const int itn = (it + 1 < iters) ? it + 1 : it;   // tail: redundant reload
        {
            const float* g = x + (size_t)((t0 + itn * stride) * TROWS + srow) * FEAT + schunk * 8;
            pf0 = ((const floatx4*)g)[0];
            pf1 = ((const floatx4*)g)[1];
        }

        // ---- barrier WITHOUT vmcnt drain: only LDS ops must be visible.
        asm volatile("s_waitcnt lgkmcnt(0)" ::: "memory");
        __builtin_amdgcn_sched_barrier(0);
        __builtin_amdgcn_s_barrier();
        __builtin_amdgcn_sched_barrier(0);

        // ---- MFMA over K=256: stream Af, 2 acc chains (swapped operands:
        // D[m=out-col][n=x-row]; C/D: col(lane&15)=x-row, row(grp*4+r)=out-col)
        floatx4 acc[2] = {{0.f,0.f,0.f,0.f},{0.f,0.f,0.f,0.f}};
        #pragma unroll
        for (int ks = 0; ks < 8; ++ks) {
            short8 af = *(const short8*)(pb + rdoff + ks * 1024);
            acc[0] = __builtin_amdgcn_mfma_f32_16x16x32_bf16(Bf[0][ks], af, acc[0], 0, 0, 0);
            acc[1] = __builtin_amdgcn_mfma_f32_16x16x32_bf16(Bf[1][ks], af, acc[1], 0, 0, 0);
        }

        // ---- epilogue: y = x * rsqrt(acc + beta_c); x re-read is L2-hot.
        const int rb = (t0 + it * stride) * TROWS;
        const float* xr   = x   + (size_t)(rb + l15) * FEAT + colbase + grp * 4;
        float*       orow = out + (size_t)(rb + l15) * FEAT + colbase + grp * 4;
        #pragma unroll
        for (int nt = 0; nt < 2; ++nt) {
            floatx4 xv = *(const floatx4*)(xr + nt * 16);
            floatx4 y;
            #pragma unroll
            for (int r = 0; r < 4; ++r)
                y[r] = xv[r] * rsqrtf(acc[nt][r] + bc4[nt][r]);
            *(floatx4*)(orow + nt * 16) = y;
        }
        // no vmcnt drain; next iter's cvt waits on pf via compiler vmcnt.
    }
}

extern "C" void kernel_launch(void* const* d_in, const int* in_sizes, int n_in,
                              void* d_out, int out_size, void* d_ws, size_t ws_size,
                              hipStream_t stream) {
    const float* x     = (const float*)d_in[0];
    const float* beta  = (const float*)d_in[1];
    const float* gamma = (const float*)d_in[2];
    float* out = (float*)d_out;

    const int batch = in_sizes[0] / FEAT;   // 262144

    dim3 grid(512);     // 2 blocks/CU x 8 waves = 16 waves/CU = 4 waves/SIMD
    dim3 block(512);
    hipLaunchKernelGGL(gdn_kernel, grid, block, 0, stream,
                       x, beta, gamma, out, batch);
}

// Round 10
// 128.941 us; speedup vs baseline: 2.4860x; 1.1515x over previous
//
#include <hip/hip_runtime.h>
#include <hip/hip_bf16.h>

#define FEAT   256
#define TROWS  16
#define PBYTES (TROWS * FEAT * 2)   // 8 KiB bf16 x^2 tile (single buffer)
#define RSOFF  PBYTES               // rs tile starts after P
#define RSBYTES (TROWS * FEAT * 4)  // 16 KiB f32 rsqrt-factor tile

typedef __attribute__((ext_vector_type(8))) short  short8;
typedef __attribute__((ext_vector_type(4))) float  floatx4;

__device__ __forceinline__ short f2bf(float f) {
    __hip_bfloat16 h = __float2bfloat16(f);   // RTNE; pairs fuse to v_cvt_pk_bf16_f32
    return __builtin_bit_cast(short, h);
}

// R10: x touches global exactly once (load), once (store).
// Per iter: thread t (srow=t&15, schunk=t>>4) holds x[rb+srow][schunk*8..+8]
// in regs (prefetched 1 iter ahead).
//   stage:   square+cvt -> ds_write_b128 into P tile [chunk][row]
//   barrier A
//   mfma:    wave w (32 out-cols): 8x ds_read_b128 P-frags, 16 MFMA (swapped:
//            D[out-col][x-row]), rs = rsqrt(acc+bc), 2x ds_write_b128 into
//            RS tile [row][col] (XOR-swizzled: colbytes ^= (row&7)<<4)
//   barrier B
//   epilogue: 2x ds_read_b128 rs (same swizzle), y = x_reg * rs,
//            2x global_store_dwordx4
// Race-safety with SINGLE P and RS buffers: P-write(it+1) only happens after
// the wave passed barrier B(it), which all waves pass only after consuming
// P-reads(it); RS-write(it+1) is after barrier A(it+1) > RS-read(it). 24 KiB LDS.
__global__ __launch_bounds__(512, 4) void gdn_kernel(
    const float* __restrict__ x,
    const float* __restrict__ beta,
    const float* __restrict__ gamma,
    float* __restrict__ out,
    int batch)
{
    __shared__ char lds[PBYTES + RSBYTES];

    const int tid  = threadIdx.x;
    const int lane = tid & 63;
    const int wave = tid >> 6;          // 0..7 -> 32-col slice
    const int l15  = lane & 15;
    const int grp  = lane >> 4;
    const int colbase = wave * 32;

    // ---- One-time: gamma fragments (A-operand of swapped MFMA), 64 regs.
    // k-hat map k = ks*32 + grp*8 + i, shared by both operands (HW-verified
    // self-consistent: R7/R9 pass).
    short8 Bf[2][8];
    #pragma unroll
    for (int nt = 0; nt < 2; ++nt) {
        const int col = colbase + nt * 16 + l15;
        #pragma unroll
        for (int ks = 0; ks < 8; ++ks) {
            const int k0 = ks * 32 + grp * 8;
            short8 b;
            #pragma unroll
            for (int i = 0; i < 8; ++i)
                b[i] = f2bf(gamma[(size_t)(k0 + i) * FEAT + col]);
            Bf[nt][ks] = b;
        }
    }

    // beta_c per (nt, r): out-cols colbase + nt*16 + grp*4 + r
    floatx4 bc4[2];
    #pragma unroll
    for (int nt = 0; nt < 2; ++nt) {
        floatx4 b = *(const floatx4*)(beta + colbase + nt * 16 + grp * 4);
        #pragma unroll
        for (int r = 0; r < 4; ++r) bc4[nt][r] = fmaxf(b[r], 1e-6f);
    }

    const int stride = gridDim.x;                 // 512
    const int iters  = (batch / TROWS) / stride;  // 32 (exact)
    const int t0     = blockIdx.x;

    const int srow   = tid & 15;        // staging row within tile
    const int schunk = tid >> 4;        // staging 8-float k/col chunk (0..31)
    const int rdoff  = grp * 256 + l15 * 16;      // P frag-read base

    // RS addressing (XOR-swizzle col-bytes with row&7, involution both sides)
    const unsigned rs_w0 = (unsigned)(l15 * 1024 + (((colbase + grp * 4) * 4) ^ ((l15 & 7) << 4)));
    const unsigned rs_w1 = (unsigned)(l15 * 1024 + (((colbase + 16 + grp * 4) * 4) ^ ((l15 & 7) << 4)));
    const unsigned rs_r0 = (unsigned)(srow * 1024 + ((schunk * 32)      ^ ((srow & 7) << 4)));
    const unsigned rs_r1 = (unsigned)(srow * 1024 + ((schunk * 32 + 16) ^ ((srow & 7) << 4)));

    // Prologue: prefetch tile t0 into regs.
    floatx4 pf0, pf1;
    {
        const float* g = x + (size_t)(t0 * TROWS + srow) * FEAT + schunk * 8;
        pf0 = ((const floatx4*)g)[0];
        pf1 = ((const floatx4*)g)[1];
    }

    for (int it = 0; it < iters; ++it) {
        // ---- stage: x^2 -> bf16 -> P tile (one b128 write/thread)
        short8 w;
        #pragma unroll
        for (int i = 0; i < 4; ++i) {
            w[i]     = f2bf(pf0[i] * pf0[i]);
            w[4 + i] = f2bf(pf1[i] * pf1[i]);
        }
        *(short8*)(lds + tid * 16) = w;

        // keep x for the final multiply; issue next prefetch (rides across barriers)
        const floatx4 xs0 = pf0, xs1 = pf1;
        const int itn = (it + 1 < iters) ? it + 1 : it;   // tail: redundant reload
        {
            const float* g = x + (size_t)((t0 + itn * stride) * TROWS + srow) * FEAT + schunk * 8;
            pf0 = ((const floatx4*)g)[0];
            pf1 = ((const floatx4*)g)[1];
        }

        // ---- barrier A (LDS visibility only; no vmcnt drain)
        asm volatile("s_waitcnt lgkmcnt(0)" ::: "memory");
        __builtin_amdgcn_sched_barrier(0);
        __builtin_amdgcn_s_barrier();
        __builtin_amdgcn_sched_barrier(0);

        // ---- MFMA over K=256 (swapped): acc[nt][r] = norm_pool(row=l15,
        // col=colbase+nt*16+grp*4+r)
        floatx4 acc[2] = {{0.f,0.f,0.f,0.f},{0.f,0.f,0.f,0.f}};
        #pragma unroll
        for (int ks = 0; ks < 8; ++ks) {
            short8 af = *(const short8*)(lds + rdoff + ks * 1024);
            acc[0] = __builtin_amdgcn_mfma_f32_16x16x32_bf16(Bf[0][ks], af, acc[0], 0, 0, 0);
            acc[1] = __builtin_amdgcn_mfma_f32_16x16x32_bf16(Bf[1][ks], af, acc[1], 0, 0, 0);
        }

        // ---- rs = rsqrt(acc + bc) -> RS tile (swizzled, 2-way banks)
        floatx4 rs0, rs1;
        #pragma unroll
        for (int r = 0; r < 4; ++r) {
            rs0[r] = rsqrtf(acc[0][r] + bc4[0][r]);
            rs1[r] = rsqrtf(acc[1][r] + bc4[1][r]);
        }
        *(floatx4*)(lds + RSOFF + rs_w0) = rs0;
        *(floatx4*)(lds + RSOFF + rs_w1) = rs1;

        // ---- barrier B
        asm volatile("s_waitcnt lgkmcnt(0)" ::: "memory");
        __builtin_amdgcn_sched_barrier(0);
        __builtin_amdgcn_s_barrier();
        __builtin_amdgcn_sched_barrier(0);

        // ---- epilogue: y = x_reg * rs, straight to global (x never re-read)
        floatx4 f0 = *(const floatx4*)(lds + RSOFF + rs_r0);
        floatx4 f1 = *(const floatx4*)(lds + RSOFF + rs_r1);
        const int rb = (t0 + it * stride) * TROWS;
        float* orow = out + (size_t)(rb + srow) * FEAT + schunk * 8;
        floatx4 y0, y1;
        #pragma unroll
        for (int i = 0; i < 4; ++i) {
            y0[i] = xs0[i] * f0[i];
            y1[i] = xs1[i] * f1[i];
        }
        ((floatx4*)orow)[0] = y0;
        ((floatx4*)orow)[1] = y1;
        // no vmcnt drain: next iter's cvt waits on pf via compiler-inserted
        // vmcnt; LDS rendezvous handled by barriers A/B.
    }
}

extern "C" void kernel_launch(void* const* d_in, const int* in_sizes, int n_in,
                              void* d_out, int out_size, void* d_ws, size_t ws_size,
                              hipStream_t stream) {
    const float* x     = (const float*)d_in[0];
    const float* beta  = (const float*)d_in[1];
    const float* gamma = (const float*)d_in[2];
    float* out = (float*)d_out;

    const int batch = in_sizes[0] / FEAT;   // 262144

    dim3 grid(512);     // 2 blocks/CU x 8 waves = 16 waves/CU = 4 waves/SIMD
    dim3 block(512);
    hipLaunchKernelGGL(gdn_kernel, grid, block, 0, stream,
                       x, beta, gamma, out, batch);
}